// Round 13
// baseline (270.568 us; speedup 1.0000x reference)
//
#include <hip/hip_runtime.h>
#include <stdint.h>

typedef unsigned short u16;
typedef _Float16 f16;
typedef __fp16 fp16x2 __attribute__((ext_vector_type(2)));
typedef f16 f16x4 __attribute__((ext_vector_type(4)));
typedef f16 f16x8 __attribute__((ext_vector_type(8)));
typedef float f32x4 __attribute__((ext_vector_type(4)));
typedef u16 u16x8v __attribute__((ext_vector_type(8)));
typedef uint32_t u32x4 __attribute__((ext_vector_type(4)));

#define MFMAH  __builtin_amdgcn_mfma_f32_16x16x32_f16

// ---------- helpers ----------
__device__ __forceinline__ void gload16(const void* g, void* l) {
    __builtin_amdgcn_global_load_lds(
        (const __attribute__((address_space(1))) uint32_t*)g,
        (__attribute__((address_space(3))) uint32_t*)l, 16, 0, 0);
}

// ---------- conversion kernels (r12-exact) ----------
__global__ __launch_bounds__(256) void convert_x(const float4* __restrict__ x,
                                                 f16x8* __restrict__ o) {
    int i = blockIdx.x * 256 + threadIdx.x;
    float4 a = x[2 * i], b = x[2 * i + 1];
    f16x8 h;
    h[0] = (f16)a.x; h[1] = (f16)a.y; h[2] = (f16)a.z; h[3] = (f16)a.w;
    h[4] = (f16)b.x; h[5] = (f16)b.y; h[6] = (f16)b.z; h[7] = (f16)b.w;
    o[i] = h;
}

__global__ __launch_bounds__(256) void convert_w(const float4* __restrict__ Wq,
                                                 const float4* __restrict__ Wk,
                                                 const float4* __restrict__ Wv,
                                                 const float4* __restrict__ Wo,
                                                 f16x8* __restrict__ hi) {
    int gi = blockIdx.x * 256 + threadIdx.x;
    int wsel = gi >> 17;
    int li = gi & 131071;
    const float4* src = (wsel == 0) ? Wq : (wsel == 1) ? Wk : (wsel == 2) ? Wv : Wo;
    float4 a = src[2 * li], b = src[2 * li + 1];
    float v[8] = {a.x, a.y, a.z, a.w, b.x, b.y, b.z, b.w};
    f16x8 h;
#pragma unroll
    for (int j = 0; j < 8; ++j) h[j] = (f16)v[j];
    hi[gi] = h;
}

// ---------- fused QKV GEMM: 512 threads, M256 x N128, BK=64 (r12-exact) ----
__global__ __launch_bounds__(512, 4)
void gemm_qkv(const f16* __restrict__ A,
              const f16* __restrict__ Whi,
              const float* __restrict__ b0, const float* __restrict__ b1,
              const float* __restrict__ b2,
              f16* __restrict__ oq, f16* __restrict__ ok, f16* __restrict__ ov) {
    __shared__ f16 ldsA[256 * 64];      // 32 KB
    __shared__ f16 ldsW[128 * 64];      // 16 KB
    const int t = threadIdx.x;
    const int lane = t & 63, quad = lane >> 4, l16 = lane & 15;
    const int wid = t >> 6;             // 0..7
    const int wsel = blockIdx.x >> 3;
    const int bm = blockIdx.y * 256;
    const int bn = (blockIdx.x & 7) * 128;
    const int wm = (wid >> 1) * 64, wn = (wid & 1) * 64;
    const f16* Wh = Whi + (size_t)wsel * 1048576;
    const float* bias = (wsel == 0) ? b0 : (wsel == 1) ? b1 : b2;

    f32x4 acc[4][4] = {};

    for (int kt = 0; kt < 16; ++kt) {
        __syncthreads();
        const int k0 = kt * 64;
#pragma unroll
        for (int c = 0; c < 4; ++c) {
            const int u = c * 512 + t;
            const int r = u >> 3, cc = u & 7;
            const int sc = cc ^ (r & 7);
            gload16(A + (size_t)(bm + r) * 1024 + k0 + sc * 8, &ldsA[u * 8]);
        }
#pragma unroll
        for (int c = 0; c < 2; ++c) {
            const int u = c * 512 + t;
            const int r = u >> 3, cc = u & 7;
            const int sc = cc ^ (r & 7);
            gload16(Wh + (size_t)(bn + r) * 1024 + k0 + sc * 8, &ldsW[u * 8]);
        }
        __syncthreads();

#pragma unroll
        for (int kq = 0; kq < 2; ++kq) {
            f16x8 bh[4];
            const int ch = (kq * 4 + quad) ^ (l16 & 7);
#pragma unroll
            for (int i = 0; i < 4; ++i) {
                const int rb = wn + i * 16 + l16;
                bh[i] = *(const f16x8*)&ldsW[rb * 64 + ch * 8];
            }
#pragma unroll
            for (int mi = 0; mi < 4; ++mi) {
                const int ra = wm + mi * 16 + l16;
                const f16x8 af = *(const f16x8*)&ldsA[ra * 64 + ch * 8];
#pragma unroll
                for (int ni = 0; ni < 4; ++ni)
                    acc[mi][ni] = MFMAH(af, bh[ni], acc[mi][ni], 0, 0, 0);
            }
        }
    }

#pragma unroll
    for (int ni = 0; ni < 4; ++ni) {
        const int e = bn + wn + ni * 16 + l16;
        const float bv = bias[e];
        const int h = e >> 6, d = e & 63;
#pragma unroll
        for (int mi = 0; mi < 4; ++mi) {
            const int row0 = bm + wm + mi * 16 + quad * 4;
            if (wsel == 2) {                    // V -> [B,H,Hd,S]
                const int b = row0 >> 11, s0 = row0 & 2047;
                ushort4 pk;
                f16 p0 = (f16)(acc[mi][ni][0] + bv);
                f16 p1 = (f16)(acc[mi][ni][1] + bv);
                f16 p2 = (f16)(acc[mi][ni][2] + bv);
                f16 p3 = (f16)(acc[mi][ni][3] + bv);
                pk.x = __builtin_bit_cast(u16, p0);
                pk.y = __builtin_bit_cast(u16, p1);
                pk.z = __builtin_bit_cast(u16, p2);
                pk.w = __builtin_bit_cast(u16, p3);
                *(ushort4*)(ov + ((size_t)((b * 16 + h) * 64 + d)) * 2048 + s0) = pk;
            } else {                            // Q or K -> [B,H,S,Hd]
                f16* dst = (wsel == 0) ? oq : ok;
#pragma unroll
                for (int r = 0; r < 4; ++r) {
                    const int row = row0 + r;
                    const int b = row >> 11, s = row & 2047;
                    float v = acc[mi][ni][r] + bv;
                    if (wsel == 0) v *= 0.18033688f;   // log2(e)/8
                    dst[((size_t)((b * 16 + h) * 2048 + s)) * 64 + d] = (f16)v;
                }
            }
        }
    }
}

// ---------- O-projection GEMM (r12-exact: single-plane W) ------
__global__ __launch_bounds__(256, 2)
void gemm_o(const f16* __restrict__ A,
            const f16* __restrict__ Wh,
            const float* __restrict__ bias, float* __restrict__ ofp) {
    __shared__ f16 ldsA[128 * 64];      // 16 KB
    __shared__ f16 ldsW[128 * 64];      // 16 KB
    const int t = threadIdx.x;
    const int lane = t & 63, quad = lane >> 4, l16 = lane & 15;
    const int wid = t >> 6;
    const int bm = blockIdx.y * 128, bn = blockIdx.x * 128;
    const int wm = (wid >> 1) * 64, wn = (wid & 1) * 64;

    f32x4 acc[4][4] = {};

    for (int kt = 0; kt < 16; ++kt) {
        __syncthreads();
        const int k0 = kt * 64;
#pragma unroll
        for (int c = 0; c < 4; ++c) {
            const int u = c * 256 + t;
            const int r = u >> 3, cc = u & 7;
            const int sc = cc ^ (r & 7);
            gload16(A + (size_t)(bm + r) * 1024 + k0 + sc * 8, &ldsA[u * 8]);
        }
#pragma unroll
        for (int c = 0; c < 4; ++c) {
            const int u = c * 256 + t;
            const int r = u >> 3, cc = u & 7;
            const int sc = cc ^ (r & 7);
            gload16(Wh + (size_t)(bn + r) * 1024 + k0 + sc * 8, &ldsW[u * 8]);
        }
        __syncthreads();

#pragma unroll
        for (int kq = 0; kq < 2; ++kq) {
            f16x8 bh[4];
            const int ch = (kq * 4 + quad) ^ (l16 & 7);
#pragma unroll
            for (int i = 0; i < 4; ++i) {
                const int rb = wn + i * 16 + l16;
                bh[i] = *(const f16x8*)&ldsW[rb * 64 + ch * 8];
            }
#pragma unroll
            for (int mi = 0; mi < 4; ++mi) {
                const int ra = wm + mi * 16 + l16;
                const f16x8 af = *(const f16x8*)&ldsA[ra * 64 + ch * 8];
#pragma unroll
                for (int ni = 0; ni < 4; ++ni)
                    acc[mi][ni] = MFMAH(af, bh[ni], acc[mi][ni], 0, 0, 0);
            }
        }
    }

#pragma unroll
    for (int ni = 0; ni < 4; ++ni) {
        const int e = bn + wn + ni * 16 + l16;
        const float bv = bias[e];
#pragma unroll
        for (int mi = 0; mi < 4; ++mi) {
            const int row0 = bm + wm + mi * 16 + quad * 4;
#pragma unroll
            for (int r = 0; r < 4; ++r)
                ofp[(size_t)(row0 + r) * 1024 + e] = acc[mi][ni][r] + bv;
        }
    }
}

// ---------- flash attention (K=32 PV + setprio + 2-deep kk pipeline) ----
// T15 att[2]: slices kk are independent; order S(0) S(1) PV(0) S(2) PV(1)
// S(3) PV(2) PV(3) gives the scheduler PV-MFMA work to co-issue against
// each slice's exp2 (TRANS) + cvt_pkrtz (VALU). of/rs still accumulate in
// kk order -> bit-identical output.
__global__ __launch_bounds__(512, 4)
void attn_fused(const f16* __restrict__ Q, const f16* __restrict__ K,
                const f16* __restrict__ Vt, f16* __restrict__ AO) {
    __shared__ f16 Kt[2][128 * 64];   // 16 KB each
    __shared__ f16 Vs[2][64 * 128];   // 16 KB each
    const int t = threadIdx.x, wid = t >> 6, lane = t & 63;
    const int quad = lane >> 4, l16 = lane & 15;
    const int sw7 = l16 & 7;
    const int bh = blockIdx.x;
    const int q0 = blockIdx.y * 256;
    const size_t base = (size_t)bh * (2048 * 64);

    const u16x8v ou = {0x3C00, 0x3C00, 0x3C00, 0x3C00, 0x3C00, 0x3C00, 0x3C00, 0x3C00};
    const f16x8 ONES8 = __builtin_bit_cast(f16x8, ou);

    f16x8 qf[2][2];
#pragma unroll
    for (int s = 0; s < 2; ++s) {
        const int qrow = q0 + wid * 32 + s * 16 + l16;
        qf[s][0] = *(const f16x8*)(Q + base + (size_t)qrow * 64 + quad * 8);
        qf[s][1] = *(const f16x8*)(Q + base + (size_t)qrow * 64 + 32 + quad * 8);
    }

    f32x4 of[2][4] = {};   // of[s][di] = O^T tile: row d'=quad*4+r, col q=l16
    f32x4 rs[2] = {};

    auto STAGE = [&](int bf, int kt) {
#pragma unroll
        for (int c = 0; c < 2; ++c) {           // K tile: 128 rows x 64 d
            const int u = c * 512 + t;
            const int row = u >> 3, cc = u & 7;
            const int sc = cc ^ (row & 7);
            gload16(K + base + (size_t)(kt * 128 + row) * 64 + sc * 8, &Kt[bf][u * 8]);
        }
#pragma unroll
        for (int c = 0; c < 2; ++c) {           // V^T tile: 64 d x 128 k
            const int u = c * 512 + t;
            const int row = u >> 4, cc = u & 15;
            const int sc = cc ^ (row & 15);
            gload16(Vt + base + (size_t)row * 2048 + kt * 128 + sc * 8, &Vs[bf][u * 8]);
        }
    };

    STAGE(0, 0);
    __syncthreads();                 // implicit vmcnt(0) drain

    for (int kt = 0; kt < 16; ++kt) {
        const int bf = kt & 1;
        if (kt < 15) STAGE(bf ^ 1, kt + 1);   // prefetch in flight over compute

        // --- S slice: S^T MFMA + exp2 -> packed K=32 P B-fragment dwords ---
        auto S_SLICE = [&](int kk, u32x4* pws) {
#pragma unroll
            for (int nn = 0; nn < 2; ++nn) {
                const int krow = (kk * 2 + nn) * 16 + l16;
                const f16x8 kb0 = *(const f16x8*)&Kt[bf][krow * 64 + (quad ^ sw7) * 8];
                const f16x8 kb1 = *(const f16x8*)&Kt[bf][krow * 64 + ((4 | quad) ^ sw7) * 8];
#pragma unroll
                for (int s = 0; s < 2; ++s) {
                    f32x4 sf = {};
                    sf = MFMAH(kb0, qf[s][0], sf, 0, 0, 0);   // A=K, B=Q -> S^T
                    sf = MFMAH(kb1, qf[s][1], sf, 0, 0, 0);
                    const float p0 = __builtin_amdgcn_exp2f(sf[0]);
                    const float p1 = __builtin_amdgcn_exp2f(sf[1]);
                    const float p2 = __builtin_amdgcn_exp2f(sf[2]);
                    const float p3 = __builtin_amdgcn_exp2f(sf[3]);
                    pws[s][nn * 2 + 0] = __builtin_bit_cast(uint32_t, __builtin_amdgcn_cvt_pkrtz(p0, p1));
                    pws[s][nn * 2 + 1] = __builtin_bit_cast(uint32_t, __builtin_amdgcn_cvt_pkrtz(p2, p3));
                }
            }
        };
        // --- PV slice: O^T += V^T P (K=32, permuted-k A-fragment) + rowsum ---
        auto PV_SLICE = [&](int kk, const u32x4* pws) {
            f16x8 pf8[2];
            pf8[0] = __builtin_bit_cast(f16x8, pws[0]);
            pf8[1] = __builtin_bit_cast(f16x8, pws[1]);
            __builtin_amdgcn_s_setprio(1);
#pragma unroll
            for (int di = 0; di < 4; ++di) {
                const int row = di * 16 + l16;
                const int col0 = kk * 32 + quad * 4;          // nn0 block
                const int ch0 = (col0 >> 3) ^ (row & 15);
                const f16x4 v0 = *(const f16x4*)&Vs[bf][row * 128 + ch0 * 8 + (quad & 1) * 4];
                const int col1 = col0 + 16;                   // nn1 block
                const int ch1 = (col1 >> 3) ^ (row & 15);
                const f16x4 v1 = *(const f16x4*)&Vs[bf][row * 128 + ch1 * 8 + (quad & 1) * 4];
                const f16x8 vb8 = __builtin_shufflevector(v0, v1, 0, 1, 2, 3, 4, 5, 6, 7);
#pragma unroll
                for (int s = 0; s < 2; ++s)
                    of[s][di] = MFMAH(vb8, pf8[s], of[s][di], 0, 0, 0);
            }
#pragma unroll
            for (int s = 0; s < 2; ++s)
                rs[s] = MFMAH(ONES8, pf8[s], rs[s], 0, 0, 0);
            __builtin_amdgcn_s_setprio(0);
        };

        // 2-deep software pipeline over the 4 independent kk slices
        u32x4 pA[2], pB[2];
        S_SLICE(0, pA);
        S_SLICE(1, pB);
        PV_SLICE(0, pA);
        S_SLICE(2, pA);
        PV_SLICE(1, pB);
        S_SLICE(3, pB);
        PV_SLICE(2, pA);
        PV_SLICE(3, pB);

        __syncthreads();   // drains prefetch (vmcnt 0) + guards buf reuse
    }

    // epilogue: of[s][di][r] = O[qrow(l16,s)][h*64 + di*16 + quad*4 + r]
    const int b = bh >> 4, h = bh & 15;
#pragma unroll
    for (int s = 0; s < 2; ++s) {
        const int qrow = q0 + wid * 32 + s * 16 + l16;
        const float inv = 1.0f / rs[s][0];
#pragma unroll
        for (int di = 0; di < 4; ++di) {
            const int e0 = h * 64 + di * 16 + quad * 4;
            ushort4 pk;
            f16 o0 = (f16)(of[s][di][0] * inv);
            f16 o1 = (f16)(of[s][di][1] * inv);
            f16 o2 = (f16)(of[s][di][2] * inv);
            f16 o3 = (f16)(of[s][di][3] * inv);
            pk.x = __builtin_bit_cast(u16, o0);
            pk.y = __builtin_bit_cast(u16, o1);
            pk.z = __builtin_bit_cast(u16, o2);
            pk.w = __builtin_bit_cast(u16, o3);
            *(ushort4*)(AO + (size_t)(b * 2048 + qrow) * 1024 + e0) = pk;
        }
    }
}

// ---------- launch ----------
extern "C" void kernel_launch(void* const* d_in, const int* in_sizes, int n_in,
                              void* d_out, int out_size, void* d_ws, size_t ws_size,
                              hipStream_t stream) {
    const float* x  = (const float*)d_in[0];
    const float* Wq = (const float*)d_in[1];
    const float* bq = (const float*)d_in[2];
    const float* Wk = (const float*)d_in[3];
    const float* bk = (const float*)d_in[4];
    const float* Wv = (const float*)d_in[5];
    const float* bv = (const float*)d_in[6];
    const float* Wo = (const float*)d_in[7];
    const float* bo = (const float*)d_in[8];
    float* out = (float*)d_out;

    char* ws = (char*)d_ws;
    f16* XF  = (f16*)(ws);                 // 16 MB
    f16* WH  = (f16*)(ws + (16u << 20));   // 8 MB
    f16* QF  = (f16*)(ws + (32u << 20));   // 16 MB
    f16* KF  = (f16*)(ws + (48u << 20));   // 16 MB
    f16* VTF = (f16*)(ws + (64u << 20));   // 16 MB
    f16* AOF = (f16*)(ws + (80u << 20));   // 16 MB

    convert_x<<<4096, 256, 0, stream>>>((const float4*)x, (f16x8*)XF);
    convert_w<<<2048, 256, 0, stream>>>((const float4*)Wq, (const float4*)Wk,
                                        (const float4*)Wv, (const float4*)Wo,
                                        (f16x8*)WH);

    gemm_qkv<<<dim3(24, 32), 512, 0, stream>>>(XF, WH, bq, bk, bv, QF, KF, VTF);

    attn_fused<<<dim3(64, 8), 512, 0, stream>>>(QF, KF, VTF, AOF);

    gemm_o<<<dim3(8, 64), 256, 0, stream>>>(AOF, WH + 3145728, bo, out);
}

// Round 14
// 266.194 us; speedup vs baseline: 1.0164x; 1.0164x over previous
//
#include <hip/hip_runtime.h>
#include <stdint.h>

typedef unsigned short u16;
typedef _Float16 f16;
typedef __fp16 fp16x2 __attribute__((ext_vector_type(2)));
typedef f16 f16x4 __attribute__((ext_vector_type(4)));
typedef f16 f16x8 __attribute__((ext_vector_type(8)));
typedef float f32x4 __attribute__((ext_vector_type(4)));
typedef u16 u16x8v __attribute__((ext_vector_type(8)));
typedef uint32_t u32x4 __attribute__((ext_vector_type(4)));

#define MFMAH  __builtin_amdgcn_mfma_f32_16x16x32_f16

// ---------- helpers ----------
__device__ __forceinline__ void gload16(const void* g, void* l) {
    __builtin_amdgcn_global_load_lds(
        (const __attribute__((address_space(1))) uint32_t*)g,
        (__attribute__((address_space(3))) uint32_t*)l, 16, 0, 0);
}

// ---------- conversion kernels (r12-exact) ----------
__global__ __launch_bounds__(256) void convert_x(const float4* __restrict__ x,
                                                 f16x8* __restrict__ o) {
    int i = blockIdx.x * 256 + threadIdx.x;
    float4 a = x[2 * i], b = x[2 * i + 1];
    f16x8 h;
    h[0] = (f16)a.x; h[1] = (f16)a.y; h[2] = (f16)a.z; h[3] = (f16)a.w;
    h[4] = (f16)b.x; h[5] = (f16)b.y; h[6] = (f16)b.z; h[7] = (f16)b.w;
    o[i] = h;
}

__global__ __launch_bounds__(256) void convert_w(const float4* __restrict__ Wq,
                                                 const float4* __restrict__ Wk,
                                                 const float4* __restrict__ Wv,
                                                 const float4* __restrict__ Wo,
                                                 f16x8* __restrict__ hi) {
    int gi = blockIdx.x * 256 + threadIdx.x;
    int wsel = gi >> 17;
    int li = gi & 131071;
    const float4* src = (wsel == 0) ? Wq : (wsel == 1) ? Wk : (wsel == 2) ? Wv : Wo;
    float4 a = src[2 * li], b = src[2 * li + 1];
    float v[8] = {a.x, a.y, a.z, a.w, b.x, b.y, b.z, b.w};
    f16x8 h;
#pragma unroll
    for (int j = 0; j < 8; ++j) h[j] = (f16)v[j];
    hi[gi] = h;
}

// ---------- fused QKV GEMM: 512 threads, M256 x N128, BK=64 ----------
// + XCD-chunked swizzle (T1): HW assigns linear workgroup id L to XCD L%8;
// remap logical=(L&7)*96+(L>>3) so each XCD owns 4 contiguous bm-groups ->
// A-tiles (2MB/XCD) stay L2-resident; A L3-traffic ~384MB -> ~16MB.
// Bijective: 768%8==0. Per-tile math unchanged -> bit-identical output.
__global__ __launch_bounds__(512, 4)
void gemm_qkv(const f16* __restrict__ A,
              const f16* __restrict__ Whi,
              const float* __restrict__ b0, const float* __restrict__ b1,
              const float* __restrict__ b2,
              f16* __restrict__ oq, f16* __restrict__ ok, f16* __restrict__ ov) {
    __shared__ f16 ldsA[256 * 64];      // 32 KB
    __shared__ f16 ldsW[128 * 64];      // 16 KB
    const int t = threadIdx.x;
    const int lane = t & 63, quad = lane >> 4, l16 = lane & 15;
    const int wid = t >> 6;             // 0..7
    const int lid = blockIdx.x + 24 * blockIdx.y;       // HW linear id
    const int logical = (lid & 7) * 96 + (lid >> 3);    // XCD-contiguous remap
    const int bx = logical % 24, by = logical / 24;
    const int wsel = bx >> 3;
    const int bm = by * 256;
    const int bn = (bx & 7) * 128;
    const int wm = (wid >> 1) * 64, wn = (wid & 1) * 64;
    const f16* Wh = Whi + (size_t)wsel * 1048576;
    const float* bias = (wsel == 0) ? b0 : (wsel == 1) ? b1 : b2;

    f32x4 acc[4][4] = {};

    for (int kt = 0; kt < 16; ++kt) {
        __syncthreads();
        const int k0 = kt * 64;
#pragma unroll
        for (int c = 0; c < 4; ++c) {
            const int u = c * 512 + t;
            const int r = u >> 3, cc = u & 7;
            const int sc = cc ^ (r & 7);
            gload16(A + (size_t)(bm + r) * 1024 + k0 + sc * 8, &ldsA[u * 8]);
        }
#pragma unroll
        for (int c = 0; c < 2; ++c) {
            const int u = c * 512 + t;
            const int r = u >> 3, cc = u & 7;
            const int sc = cc ^ (r & 7);
            gload16(Wh + (size_t)(bn + r) * 1024 + k0 + sc * 8, &ldsW[u * 8]);
        }
        __syncthreads();

#pragma unroll
        for (int kq = 0; kq < 2; ++kq) {
            f16x8 bh[4];
            const int ch = (kq * 4 + quad) ^ (l16 & 7);
#pragma unroll
            for (int i = 0; i < 4; ++i) {
                const int rb = wn + i * 16 + l16;
                bh[i] = *(const f16x8*)&ldsW[rb * 64 + ch * 8];
            }
#pragma unroll
            for (int mi = 0; mi < 4; ++mi) {
                const int ra = wm + mi * 16 + l16;
                const f16x8 af = *(const f16x8*)&ldsA[ra * 64 + ch * 8];
#pragma unroll
                for (int ni = 0; ni < 4; ++ni)
                    acc[mi][ni] = MFMAH(af, bh[ni], acc[mi][ni], 0, 0, 0);
            }
        }
    }

#pragma unroll
    for (int ni = 0; ni < 4; ++ni) {
        const int e = bn + wn + ni * 16 + l16;
        const float bv = bias[e];
        const int h = e >> 6, d = e & 63;
#pragma unroll
        for (int mi = 0; mi < 4; ++mi) {
            const int row0 = bm + wm + mi * 16 + quad * 4;
            if (wsel == 2) {                    // V -> [B,H,Hd,S]
                const int b = row0 >> 11, s0 = row0 & 2047;
                ushort4 pk;
                f16 p0 = (f16)(acc[mi][ni][0] + bv);
                f16 p1 = (f16)(acc[mi][ni][1] + bv);
                f16 p2 = (f16)(acc[mi][ni][2] + bv);
                f16 p3 = (f16)(acc[mi][ni][3] + bv);
                pk.x = __builtin_bit_cast(u16, p0);
                pk.y = __builtin_bit_cast(u16, p1);
                pk.z = __builtin_bit_cast(u16, p2);
                pk.w = __builtin_bit_cast(u16, p3);
                *(ushort4*)(ov + ((size_t)((b * 16 + h) * 64 + d)) * 2048 + s0) = pk;
            } else {                            // Q or K -> [B,H,S,Hd]
                f16* dst = (wsel == 0) ? oq : ok;
#pragma unroll
                for (int r = 0; r < 4; ++r) {
                    const int row = row0 + r;
                    const int b = row >> 11, s = row & 2047;
                    float v = acc[mi][ni][r] + bv;
                    if (wsel == 0) v *= 0.18033688f;   // log2(e)/8
                    dst[((size_t)((b * 16 + h) * 2048 + s)) * 64 + d] = (f16)v;
                }
            }
        }
    }
}

// ---------- O-projection GEMM (single-plane W + XCD swizzle) ------
__global__ __launch_bounds__(256, 2)
void gemm_o(const f16* __restrict__ A,
            const f16* __restrict__ Wh,
            const float* __restrict__ bias, float* __restrict__ ofp) {
    __shared__ f16 ldsA[128 * 64];      // 16 KB
    __shared__ f16 ldsW[128 * 64];      // 16 KB
    const int t = threadIdx.x;
    const int lane = t & 63, quad = lane >> 4, l16 = lane & 15;
    const int wid = t >> 6;
    const int lid = blockIdx.x + 8 * blockIdx.y;        // HW linear id (512 wgs)
    const int logical = (lid & 7) * 64 + (lid >> 3);    // XCD-contiguous remap
    const int bm = (logical >> 3) * 128, bn = (logical & 7) * 128;
    const int wm = (wid >> 1) * 64, wn = (wid & 1) * 64;

    f32x4 acc[4][4] = {};

    for (int kt = 0; kt < 16; ++kt) {
        __syncthreads();
        const int k0 = kt * 64;
#pragma unroll
        for (int c = 0; c < 4; ++c) {
            const int u = c * 256 + t;
            const int r = u >> 3, cc = u & 7;
            const int sc = cc ^ (r & 7);
            gload16(A + (size_t)(bm + r) * 1024 + k0 + sc * 8, &ldsA[u * 8]);
        }
#pragma unroll
        for (int c = 0; c < 4; ++c) {
            const int u = c * 256 + t;
            const int r = u >> 3, cc = u & 7;
            const int sc = cc ^ (r & 7);
            gload16(Wh + (size_t)(bn + r) * 1024 + k0 + sc * 8, &ldsW[u * 8]);
        }
        __syncthreads();

#pragma unroll
        for (int kq = 0; kq < 2; ++kq) {
            f16x8 bh[4];
            const int ch = (kq * 4 + quad) ^ (l16 & 7);
#pragma unroll
            for (int i = 0; i < 4; ++i) {
                const int rb = wn + i * 16 + l16;
                bh[i] = *(const f16x8*)&ldsW[rb * 64 + ch * 8];
            }
#pragma unroll
            for (int mi = 0; mi < 4; ++mi) {
                const int ra = wm + mi * 16 + l16;
                const f16x8 af = *(const f16x8*)&ldsA[ra * 64 + ch * 8];
#pragma unroll
                for (int ni = 0; ni < 4; ++ni)
                    acc[mi][ni] = MFMAH(af, bh[ni], acc[mi][ni], 0, 0, 0);
            }
        }
    }

#pragma unroll
    for (int ni = 0; ni < 4; ++ni) {
        const int e = bn + wn + ni * 16 + l16;
        const float bv = bias[e];
#pragma unroll
        for (int mi = 0; mi < 4; ++mi) {
            const int row0 = bm + wm + mi * 16 + quad * 4;
#pragma unroll
            for (int r = 0; r < 4; ++r)
                ofp[(size_t)(row0 + r) * 1024 + e] = acc[mi][ni][r] + bv;
        }
    }
}

// ---------- flash attention (r12-exact: K=32 PV + setprio, T15 reverted) ----
__global__ __launch_bounds__(512, 4)
void attn_fused(const f16* __restrict__ Q, const f16* __restrict__ K,
                const f16* __restrict__ Vt, f16* __restrict__ AO) {
    __shared__ f16 Kt[2][128 * 64];   // 16 KB each
    __shared__ f16 Vs[2][64 * 128];   // 16 KB each
    const int t = threadIdx.x, wid = t >> 6, lane = t & 63;
    const int quad = lane >> 4, l16 = lane & 15;
    const int sw7 = l16 & 7;
    const int bh = blockIdx.x;
    const int q0 = blockIdx.y * 256;
    const size_t base = (size_t)bh * (2048 * 64);

    const u16x8v ou = {0x3C00, 0x3C00, 0x3C00, 0x3C00, 0x3C00, 0x3C00, 0x3C00, 0x3C00};
    const f16x8 ONES8 = __builtin_bit_cast(f16x8, ou);

    f16x8 qf[2][2];
#pragma unroll
    for (int s = 0; s < 2; ++s) {
        const int qrow = q0 + wid * 32 + s * 16 + l16;
        qf[s][0] = *(const f16x8*)(Q + base + (size_t)qrow * 64 + quad * 8);
        qf[s][1] = *(const f16x8*)(Q + base + (size_t)qrow * 64 + 32 + quad * 8);
    }

    f32x4 of[2][4] = {};   // of[s][di] = O^T tile: row d'=quad*4+r, col q=l16
    f32x4 rs[2] = {};

    auto STAGE = [&](int bf, int kt) {
#pragma unroll
        for (int c = 0; c < 2; ++c) {           // K tile: 128 rows x 64 d
            const int u = c * 512 + t;
            const int row = u >> 3, cc = u & 7;
            const int sc = cc ^ (row & 7);
            gload16(K + base + (size_t)(kt * 128 + row) * 64 + sc * 8, &Kt[bf][u * 8]);
        }
#pragma unroll
        for (int c = 0; c < 2; ++c) {           // V^T tile: 64 d x 128 k
            const int u = c * 512 + t;
            const int row = u >> 4, cc = u & 15;
            const int sc = cc ^ (row & 15);
            gload16(Vt + base + (size_t)row * 2048 + kt * 128 + sc * 8, &Vs[bf][u * 8]);
        }
    };

    STAGE(0, 0);
    __syncthreads();                 // implicit vmcnt(0) drain

    for (int kt = 0; kt < 16; ++kt) {
        const int bf = kt & 1;
        if (kt < 15) STAGE(bf ^ 1, kt + 1);   // prefetch in flight over compute

#pragma unroll
        for (int kk = 0; kk < 4; ++kk) {
            // --- S^T + exp2 -> packed K=32 P B-fragments ---
            u32x4 pws[2];
#pragma unroll
            for (int nn = 0; nn < 2; ++nn) {
                const int krow = (kk * 2 + nn) * 16 + l16;
                const f16x8 kb0 = *(const f16x8*)&Kt[bf][krow * 64 + (quad ^ sw7) * 8];
                const f16x8 kb1 = *(const f16x8*)&Kt[bf][krow * 64 + ((4 | quad) ^ sw7) * 8];
#pragma unroll
                for (int s = 0; s < 2; ++s) {
                    f32x4 sf = {};
                    sf = MFMAH(kb0, qf[s][0], sf, 0, 0, 0);   // A=K, B=Q -> S^T
                    sf = MFMAH(kb1, qf[s][1], sf, 0, 0, 0);
                    const float p0 = __builtin_amdgcn_exp2f(sf[0]);
                    const float p1 = __builtin_amdgcn_exp2f(sf[1]);
                    const float p2 = __builtin_amdgcn_exp2f(sf[2]);
                    const float p3 = __builtin_amdgcn_exp2f(sf[3]);
                    pws[s][nn * 2 + 0] = __builtin_bit_cast(uint32_t, __builtin_amdgcn_cvt_pkrtz(p0, p1));
                    pws[s][nn * 2 + 1] = __builtin_bit_cast(uint32_t, __builtin_amdgcn_cvt_pkrtz(p2, p3));
                }
            }
            f16x8 pf8[2];
#pragma unroll
            for (int s = 0; s < 2; ++s)
                pf8[s] = __builtin_bit_cast(f16x8, pws[s]);

            // --- O^T += V^T P (K=32, permuted-k A-fragment) ---
            __builtin_amdgcn_s_setprio(1);
#pragma unroll
            for (int di = 0; di < 4; ++di) {
                const int row = di * 16 + l16;
                const int col0 = kk * 32 + quad * 4;          // nn0 block
                const int ch0 = (col0 >> 3) ^ (row & 15);
                const f16x4 v0 = *(const f16x4*)&Vs[bf][row * 128 + ch0 * 8 + (quad & 1) * 4];
                const int col1 = col0 + 16;                   // nn1 block
                const int ch1 = (col1 >> 3) ^ (row & 15);
                const f16x4 v1 = *(const f16x4*)&Vs[bf][row * 128 + ch1 * 8 + (quad & 1) * 4];
                const f16x8 vb8 = __builtin_shufflevector(v0, v1, 0, 1, 2, 3, 4, 5, 6, 7);
#pragma unroll
                for (int s = 0; s < 2; ++s)
                    of[s][di] = MFMAH(vb8, pf8[s], of[s][di], 0, 0, 0);
            }
#pragma unroll
            for (int s = 0; s < 2; ++s)
                rs[s] = MFMAH(ONES8, pf8[s], rs[s], 0, 0, 0);
            __builtin_amdgcn_s_setprio(0);
        }
        __syncthreads();   // drains prefetch (vmcnt 0) + guards buf reuse
    }

    // epilogue: of[s][di][r] = O[qrow(l16,s)][h*64 + di*16 + quad*4 + r]
    const int b = bh >> 4, h = bh & 15;
#pragma unroll
    for (int s = 0; s < 2; ++s) {
        const int qrow = q0 + wid * 32 + s * 16 + l16;
        const float inv = 1.0f / rs[s][0];
#pragma unroll
        for (int di = 0; di < 4; ++di) {
            const int e0 = h * 64 + di * 16 + quad * 4;
            ushort4 pk;
            f16 o0 = (f16)(of[s][di][0] * inv);
            f16 o1 = (f16)(of[s][di][1] * inv);
            f16 o2 = (f16)(of[s][di][2] * inv);
            f16 o3 = (f16)(of[s][di][3] * inv);
            pk.x = __builtin_bit_cast(u16, o0);
            pk.y = __builtin_bit_cast(u16, o1);
            pk.z = __builtin_bit_cast(u16, o2);
            pk.w = __builtin_bit_cast(u16, o3);
            *(ushort4*)(AO + (size_t)(b * 2048 + qrow) * 1024 + e0) = pk;
        }
    }
}

// ---------- launch ----------
extern "C" void kernel_launch(void* const* d_in, const int* in_sizes, int n_in,
                              void* d_out, int out_size, void* d_ws, size_t ws_size,
                              hipStream_t stream) {
    const float* x  = (const float*)d_in[0];
    const float* Wq = (const float*)d_in[1];
    const float* bq = (const float*)d_in[2];
    const float* Wk = (const float*)d_in[3];
    const float* bk = (const float*)d_in[4];
    const float* Wv = (const float*)d_in[5];
    const float* bv = (const float*)d_in[6];
    const float* Wo = (const float*)d_in[7];
    const float* bo = (const float*)d_in[8];
    float* out = (float*)d_out;

    char* ws = (char*)d_ws;
    f16* XF  = (f16*)(ws);                 // 16 MB
    f16* WH  = (f16*)(ws + (16u << 20));   // 8 MB
    f16* QF  = (f16*)(ws + (32u << 20));   // 16 MB
    f16* KF  = (f16*)(ws + (48u << 20));   // 16 MB
    f16* VTF = (f16*)(ws + (64u << 20));   // 16 MB
    f16* AOF = (f16*)(ws + (80u << 20));   // 16 MB

    convert_x<<<4096, 256, 0, stream>>>((const float4*)x, (f16x8*)XF);
    convert_w<<<2048, 256, 0, stream>>>((const float4*)Wq, (const float4*)Wk,
                                        (const float4*)Wv, (const float4*)Wo,
                                        (f16x8*)WH);

    gemm_qkv<<<dim3(24, 32), 512, 0, stream>>>(XF, WH, bq, bk, bv, QF, KF, VTF);

    attn_fused<<<dim3(64, 8), 512, 0, stream>>>(QF, KF, VTF, AOF);

    gemm_o<<<dim3(8, 64), 256, 0, stream>>>(AOF, WH + 3145728, bo, out);
}

// Round 15
// 256.234 us; speedup vs baseline: 1.0559x; 1.0389x over previous
//
#include <hip/hip_runtime.h>
#include <stdint.h>

typedef unsigned short u16;
typedef _Float16 f16;
typedef __fp16 fp16x2 __attribute__((ext_vector_type(2)));
typedef f16 f16x4 __attribute__((ext_vector_type(4)));
typedef f16 f16x8 __attribute__((ext_vector_type(8)));
typedef float f32x4 __attribute__((ext_vector_type(4)));
typedef u16 u16x8v __attribute__((ext_vector_type(8)));
typedef uint32_t u32x4 __attribute__((ext_vector_type(4)));

#define MFMAH  __builtin_amdgcn_mfma_f32_16x16x32_f16

// ---------- helpers ----------
__device__ __forceinline__ void gload16(const void* g, void* l) {
    __builtin_amdgcn_global_load_lds(
        (const __attribute__((address_space(1))) uint32_t*)g,
        (__attribute__((address_space(3))) uint32_t*)l, 16, 0, 0);
}

// ---------- merged conversion kernel (one launch instead of two) ----------
__global__ __launch_bounds__(256) void convert_all(const float4* __restrict__ x,
                                                   const float4* __restrict__ Wq,
                                                   const float4* __restrict__ Wk,
                                                   const float4* __restrict__ Wv,
                                                   const float4* __restrict__ Wo,
                                                   f16x8* __restrict__ xo,
                                                   f16x8* __restrict__ hi) {
    const int bid = blockIdx.x;
    if (bid < 4096) {                       // x -> f16
        int i = bid * 256 + threadIdx.x;
        float4 a = x[2 * i], b = x[2 * i + 1];
        f16x8 h;
        h[0] = (f16)a.x; h[1] = (f16)a.y; h[2] = (f16)a.z; h[3] = (f16)a.w;
        h[4] = (f16)b.x; h[5] = (f16)b.y; h[6] = (f16)b.z; h[7] = (f16)b.w;
        xo[i] = h;
    } else {                                // W -> f16 (single plane, all four)
        int gi = (bid - 4096) * 256 + threadIdx.x;
        int wsel = gi >> 17;
        int li = gi & 131071;
        const float4* src = (wsel == 0) ? Wq : (wsel == 1) ? Wk : (wsel == 2) ? Wv : Wo;
        float4 a = src[2 * li], b = src[2 * li + 1];
        float v[8] = {a.x, a.y, a.z, a.w, b.x, b.y, b.z, b.w};
        f16x8 h;
#pragma unroll
        for (int j = 0; j < 8; ++j) h[j] = (f16)v[j];
        hi[gi] = h;
    }
}

// ---------- fused QKV GEMM: 512 threads, M256 x N128, BK=64 ----------
// XCD-chunked swizzle (r14-proven). NEW: V epilogue transposes through LDS
// (reusing the 48KB staging LDS after the k-loop) so V^T stores are fully
// coalesced 16B lines instead of 8B scatter at 4KB stride (~12.5% line
// efficiency). Values bit-identical: same f16(acc+bias) rounding.
__global__ __launch_bounds__(512, 4)
void gemm_qkv(const f16* __restrict__ A,
              const f16* __restrict__ Whi,
              const float* __restrict__ b0, const float* __restrict__ b1,
              const float* __restrict__ b2,
              f16* __restrict__ oq, f16* __restrict__ ok, f16* __restrict__ ov) {
    __shared__ f16 shm[256 * 64 + 128 * 64];   // 48 KB: A tile | W tile
    f16* ldsA = shm;
    f16* ldsW = shm + 256 * 64;
    const int t = threadIdx.x;
    const int lane = t & 63, quad = lane >> 4, l16 = lane & 15;
    const int wid = t >> 6;             // 0..7
    const int lid = blockIdx.x + 24 * blockIdx.y;       // HW linear id
    const int logical = (lid & 7) * 96 + (lid >> 3);    // XCD-contiguous remap
    const int bx = logical % 24, by = logical / 24;
    const int wsel = bx >> 3;
    const int bm = by * 256;
    const int bn = (bx & 7) * 128;
    const int wm = (wid >> 1) * 64, wn = (wid & 1) * 64;
    const f16* Wh = Whi + (size_t)wsel * 1048576;
    const float* bias = (wsel == 0) ? b0 : (wsel == 1) ? b1 : b2;

    f32x4 acc[4][4] = {};

    for (int kt = 0; kt < 16; ++kt) {
        __syncthreads();
        const int k0 = kt * 64;
#pragma unroll
        for (int c = 0; c < 4; ++c) {
            const int u = c * 512 + t;
            const int r = u >> 3, cc = u & 7;
            const int sc = cc ^ (r & 7);
            gload16(A + (size_t)(bm + r) * 1024 + k0 + sc * 8, &ldsA[u * 8]);
        }
#pragma unroll
        for (int c = 0; c < 2; ++c) {
            const int u = c * 512 + t;
            const int r = u >> 3, cc = u & 7;
            const int sc = cc ^ (r & 7);
            gload16(Wh + (size_t)(bn + r) * 1024 + k0 + sc * 8, &ldsW[u * 8]);
        }
        __syncthreads();

#pragma unroll
        for (int kq = 0; kq < 2; ++kq) {
            f16x8 bh[4];
            const int ch = (kq * 4 + quad) ^ (l16 & 7);
#pragma unroll
            for (int i = 0; i < 4; ++i) {
                const int rb = wn + i * 16 + l16;
                bh[i] = *(const f16x8*)&ldsW[rb * 64 + ch * 8];
            }
#pragma unroll
            for (int mi = 0; mi < 4; ++mi) {
                const int ra = wm + mi * 16 + l16;
                const f16x8 af = *(const f16x8*)&ldsA[ra * 64 + ch * 8];
#pragma unroll
                for (int ni = 0; ni < 4; ++ni)
                    acc[mi][ni] = MFMAH(af, bh[ni], acc[mi][ni], 0, 0, 0);
            }
        }
    }

    if (wsel == 2) {
        // ---- V: LDS transpose -> coalesced V^T stores ----
        // tile rows bm..bm+256 (s), cols bn..bn+128 (e) in two 64-col halves.
        const int b = bm >> 11;
        const int s0b = bm & 2047;          // 256-aligned s base
        f16* ldsV = shm;                    // 64 x 260 f16 = 33.3 KB <= 48 KB
        __syncthreads();                    // k-loop LDS now dead
#pragma unroll
        for (int he = 0; he < 2; ++he) {
            if ((wid & 1) == he) {          // waves owning this wn-half
#pragma unroll
                for (int ni = 0; ni < 4; ++ni) {
                    const int c2 = ni * 16 + l16;          // col within half
                    const float bv = bias[bn + he * 64 + c2];
#pragma unroll
                    for (int mi = 0; mi < 4; ++mi) {
                        const int ls = wm + mi * 16 + quad * 4;
                        f16x4 pk;
                        pk[0] = (f16)(acc[mi][ni][0] + bv);
                        pk[1] = (f16)(acc[mi][ni][1] + bv);
                        pk[2] = (f16)(acc[mi][ni][2] + bv);
                        pk[3] = (f16)(acc[mi][ni][3] + bv);
                        *(f16x4*)&ldsV[c2 * 260 + ls] = pk;
                    }
                }
            }
            __syncthreads();
            const int h = (bn >> 6) + he;
#pragma unroll
            for (int c = 0; c < 4; ++c) {   // 64 d x 32 s-chunks of 8 f16
                const int u2 = c * 512 + t;
                const int d = u2 >> 5, sch = u2 & 31;
                const f16x8 vv = *(const f16x8*)&ldsV[d * 260 + sch * 8];
                *(f16x8*)(ov + ((size_t)((b * 16 + h) * 64 + d)) * 2048 + s0b + sch * 8) = vv;
            }
            __syncthreads();
        }
    } else {
        // ---- Q / K: unchanged coalesced scalar path ----
        f16* dst = (wsel == 0) ? oq : ok;
#pragma unroll
        for (int ni = 0; ni < 4; ++ni) {
            const int e = bn + wn + ni * 16 + l16;
            const float bv = bias[e];
            const int h = e >> 6, d = e & 63;
#pragma unroll
            for (int mi = 0; mi < 4; ++mi) {
                const int row0 = bm + wm + mi * 16 + quad * 4;
#pragma unroll
                for (int r = 0; r < 4; ++r) {
                    const int row = row0 + r;
                    const int b = row >> 11, s = row & 2047;
                    float v = acc[mi][ni][r] + bv;
                    if (wsel == 0) v *= 0.18033688f;   // log2(e)/8
                    dst[((size_t)((b * 16 + h) * 2048 + s)) * 64 + d] = (f16)v;
                }
            }
        }
    }
}

// ---------- O-projection GEMM (r14-exact: single-plane W + XCD swizzle) ----
__global__ __launch_bounds__(256, 2)
void gemm_o(const f16* __restrict__ A,
            const f16* __restrict__ Wh,
            const float* __restrict__ bias, float* __restrict__ ofp) {
    __shared__ f16 ldsA[128 * 64];      // 16 KB
    __shared__ f16 ldsW[128 * 64];      // 16 KB
    const int t = threadIdx.x;
    const int lane = t & 63, quad = lane >> 4, l16 = lane & 15;
    const int wid = t >> 6;
    const int lid = blockIdx.x + 8 * blockIdx.y;        // HW linear id (512 wgs)
    const int logical = (lid & 7) * 64 + (lid >> 3);    // XCD-contiguous remap
    const int bm = (logical >> 3) * 128, bn = (logical & 7) * 128;
    const int wm = (wid >> 1) * 64, wn = (wid & 1) * 64;

    f32x4 acc[4][4] = {};

    for (int kt = 0; kt < 16; ++kt) {
        __syncthreads();
        const int k0 = kt * 64;
#pragma unroll
        for (int c = 0; c < 4; ++c) {
            const int u = c * 256 + t;
            const int r = u >> 3, cc = u & 7;
            const int sc = cc ^ (r & 7);
            gload16(A + (size_t)(bm + r) * 1024 + k0 + sc * 8, &ldsA[u * 8]);
        }
#pragma unroll
        for (int c = 0; c < 4; ++c) {
            const int u = c * 256 + t;
            const int r = u >> 3, cc = u & 7;
            const int sc = cc ^ (r & 7);
            gload16(Wh + (size_t)(bn + r) * 1024 + k0 + sc * 8, &ldsW[u * 8]);
        }
        __syncthreads();

#pragma unroll
        for (int kq = 0; kq < 2; ++kq) {
            f16x8 bh[4];
            const int ch = (kq * 4 + quad) ^ (l16 & 7);
#pragma unroll
            for (int i = 0; i < 4; ++i) {
                const int rb = wn + i * 16 + l16;
                bh[i] = *(const f16x8*)&ldsW[rb * 64 + ch * 8];
            }
#pragma unroll
            for (int mi = 0; mi < 4; ++mi) {
                const int ra = wm + mi * 16 + l16;
                const f16x8 af = *(const f16x8*)&ldsA[ra * 64 + ch * 8];
#pragma unroll
                for (int ni = 0; ni < 4; ++ni)
                    acc[mi][ni] = MFMAH(af, bh[ni], acc[mi][ni], 0, 0, 0);
            }
        }
    }

#pragma unroll
    for (int ni = 0; ni < 4; ++ni) {
        const int e = bn + wn + ni * 16 + l16;
        const float bv = bias[e];
#pragma unroll
        for (int mi = 0; mi < 4; ++mi) {
            const int row0 = bm + wm + mi * 16 + quad * 4;
#pragma unroll
            for (int r = 0; r < 4; ++r)
                ofp[(size_t)(row0 + r) * 1024 + e] = acc[mi][ni][r] + bv;
        }
    }
}

// ---------- flash attention (r12-exact: K=32 PV + setprio) ----------
__global__ __launch_bounds__(512, 4)
void attn_fused(const f16* __restrict__ Q, const f16* __restrict__ K,
                const f16* __restrict__ Vt, f16* __restrict__ AO) {
    __shared__ f16 Kt[2][128 * 64];   // 16 KB each
    __shared__ f16 Vs[2][64 * 128];   // 16 KB each
    const int t = threadIdx.x, wid = t >> 6, lane = t & 63;
    const int quad = lane >> 4, l16 = lane & 15;
    const int sw7 = l16 & 7;
    const int bh = blockIdx.x;
    const int q0 = blockIdx.y * 256;
    const size_t base = (size_t)bh * (2048 * 64);

    const u16x8v ou = {0x3C00, 0x3C00, 0x3C00, 0x3C00, 0x3C00, 0x3C00, 0x3C00, 0x3C00};
    const f16x8 ONES8 = __builtin_bit_cast(f16x8, ou);

    f16x8 qf[2][2];
#pragma unroll
    for (int s = 0; s < 2; ++s) {
        const int qrow = q0 + wid * 32 + s * 16 + l16;
        qf[s][0] = *(const f16x8*)(Q + base + (size_t)qrow * 64 + quad * 8);
        qf[s][1] = *(const f16x8*)(Q + base + (size_t)qrow * 64 + 32 + quad * 8);
    }

    f32x4 of[2][4] = {};   // of[s][di] = O^T tile: row d'=quad*4+r, col q=l16
    f32x4 rs[2] = {};

    auto STAGE = [&](int bf, int kt) {
#pragma unroll
        for (int c = 0; c < 2; ++c) {           // K tile: 128 rows x 64 d
            const int u = c * 512 + t;
            const int row = u >> 3, cc = u & 7;
            const int sc = cc ^ (row & 7);
            gload16(K + base + (size_t)(kt * 128 + row) * 64 + sc * 8, &Kt[bf][u * 8]);
        }
#pragma unroll
        for (int c = 0; c < 2; ++c) {           // V^T tile: 64 d x 128 k
            const int u = c * 512 + t;
            const int row = u >> 4, cc = u & 15;
            const int sc = cc ^ (row & 15);
            gload16(Vt + base + (size_t)row * 2048 + kt * 128 + sc * 8, &Vs[bf][u * 8]);
        }
    };

    STAGE(0, 0);
    __syncthreads();                 // implicit vmcnt(0) drain

    for (int kt = 0; kt < 16; ++kt) {
        const int bf = kt & 1;
        if (kt < 15) STAGE(bf ^ 1, kt + 1);   // prefetch in flight over compute

#pragma unroll
        for (int kk = 0; kk < 4; ++kk) {
            // --- S^T + exp2 -> packed K=32 P B-fragments ---
            u32x4 pws[2];
#pragma unroll
            for (int nn = 0; nn < 2; ++nn) {
                const int krow = (kk * 2 + nn) * 16 + l16;
                const f16x8 kb0 = *(const f16x8*)&Kt[bf][krow * 64 + (quad ^ sw7) * 8];
                const f16x8 kb1 = *(const f16x8*)&Kt[bf][krow * 64 + ((4 | quad) ^ sw7) * 8];
#pragma unroll
                for (int s = 0; s < 2; ++s) {
                    f32x4 sf = {};
                    sf = MFMAH(kb0, qf[s][0], sf, 0, 0, 0);   // A=K, B=Q -> S^T
                    sf = MFMAH(kb1, qf[s][1], sf, 0, 0, 0);
                    const float p0 = __builtin_amdgcn_exp2f(sf[0]);
                    const float p1 = __builtin_amdgcn_exp2f(sf[1]);
                    const float p2 = __builtin_amdgcn_exp2f(sf[2]);
                    const float p3 = __builtin_amdgcn_exp2f(sf[3]);
                    pws[s][nn * 2 + 0] = __builtin_bit_cast(uint32_t, __builtin_amdgcn_cvt_pkrtz(p0, p1));
                    pws[s][nn * 2 + 1] = __builtin_bit_cast(uint32_t, __builtin_amdgcn_cvt_pkrtz(p2, p3));
                }
            }
            f16x8 pf8[2];
#pragma unroll
            for (int s = 0; s < 2; ++s)
                pf8[s] = __builtin_bit_cast(f16x8, pws[s]);

            // --- O^T += V^T P (K=32, permuted-k A-fragment) ---
            __builtin_amdgcn_s_setprio(1);
#pragma unroll
            for (int di = 0; di < 4; ++di) {
                const int row = di * 16 + l16;
                const int col0 = kk * 32 + quad * 4;          // nn0 block
                const int ch0 = (col0 >> 3) ^ (row & 15);
                const f16x4 v0 = *(const f16x4*)&Vs[bf][row * 128 + ch0 * 8 + (quad & 1) * 4];
                const int col1 = col0 + 16;                   // nn1 block
                const int ch1 = (col1 >> 3) ^ (row & 15);
                const f16x4 v1 = *(const f16x4*)&Vs[bf][row * 128 + ch1 * 8 + (quad & 1) * 4];
                const f16x8 vb8 = __builtin_shufflevector(v0, v1, 0, 1, 2, 3, 4, 5, 6, 7);
#pragma unroll
                for (int s = 0; s < 2; ++s)
                    of[s][di] = MFMAH(vb8, pf8[s], of[s][di], 0, 0, 0);
            }
#pragma unroll
            for (int s = 0; s < 2; ++s)
                rs[s] = MFMAH(ONES8, pf8[s], rs[s], 0, 0, 0);
            __builtin_amdgcn_s_setprio(0);
        }
        __syncthreads();   // drains prefetch (vmcnt 0) + guards buf reuse
    }

    // epilogue: of[s][di][r] = O[qrow(l16,s)][h*64 + di*16 + quad*4 + r]
    const int b = bh >> 4, h = bh & 15;
#pragma unroll
    for (int s = 0; s < 2; ++s) {
        const int qrow = q0 + wid * 32 + s * 16 + l16;
        const float inv = 1.0f / rs[s][0];
#pragma unroll
        for (int di = 0; di < 4; ++di) {
            const int e0 = h * 64 + di * 16 + quad * 4;
            ushort4 pk;
            f16 o0 = (f16)(of[s][di][0] * inv);
            f16 o1 = (f16)(of[s][di][1] * inv);
            f16 o2 = (f16)(of[s][di][2] * inv);
            f16 o3 = (f16)(of[s][di][3] * inv);
            pk.x = __builtin_bit_cast(u16, o0);
            pk.y = __builtin_bit_cast(u16, o1);
            pk.z = __builtin_bit_cast(u16, o2);
            pk.w = __builtin_bit_cast(u16, o3);
            *(ushort4*)(AO + (size_t)(b * 2048 + qrow) * 1024 + e0) = pk;
        }
    }
}

// ---------- launch ----------
extern "C" void kernel_launch(void* const* d_in, const int* in_sizes, int n_in,
                              void* d_out, int out_size, void* d_ws, size_t ws_size,
                              hipStream_t stream) {
    const float* x  = (const float*)d_in[0];
    const float* Wq = (const float*)d_in[1];
    const float* bq = (const float*)d_in[2];
    const float* Wk = (const float*)d_in[3];
    const float* bk = (const float*)d_in[4];
    const float* Wv = (const float*)d_in[5];
    const float* bv = (const float*)d_in[6];
    const float* Wo = (const float*)d_in[7];
    const float* bo = (const float*)d_in[8];
    float* out = (float*)d_out;

    char* ws = (char*)d_ws;
    f16* XF  = (f16*)(ws);                 // 16 MB
    f16* WH  = (f16*)(ws + (16u << 20));   // 8 MB
    f16* QF  = (f16*)(ws + (32u << 20));   // 16 MB
    f16* KF  = (f16*)(ws + (48u << 20));   // 16 MB
    f16* VTF = (f16*)(ws + (64u << 20));   // 16 MB
    f16* AOF = (f16*)(ws + (80u << 20));   // 16 MB

    convert_all<<<6144, 256, 0, stream>>>((const float4*)x,
                                          (const float4*)Wq, (const float4*)Wk,
                                          (const float4*)Wv, (const float4*)Wo,
                                          (f16x8*)XF, (f16x8*)WH);

    gemm_qkv<<<dim3(24, 32), 512, 0, stream>>>(XF, WH, bq, bk, bv, QF, KF, VTF);

    attn_fused<<<dim3(64, 8), 512, 0, stream>>>(QF, KF, VTF, AOF);

    gemm_o<<<dim3(8, 64), 256, 0, stream>>>(AOF, WH + 3145728, bo, out);
}